// Round 3
// baseline (11396.870 us; speedup 1.0000x reference)
//
#include <hip/hip_runtime.h>
#include <hip/hip_bf16.h>
#include <math.h>

// GRU encoder: B=64, T=1024, V=32000, E=256, U=1024, gates [z,r,h], reset_after.
// Round 5: persistent kernel + cheap barrier + REGISTER-PINNED weights.
//   - Round-4 post-mortem: VGPR_Count=172 proved weights were NOT register-
//     resident: the loop's asm"memory"/atomics/fence block LICM, so all 60
//     weight fragments (960B/thread) were re-loaded from LLC EVERY step
//     (~61 MB/step, ~5-6us) -- the dominant cost behind 11us/step.
//   - Fix: opaque asm "+v" pin on each weight fragment after the one-time
//     pre-loop load. Compiler cannot rematerialize -> weights live in VGPRs
//     for all 1024 steps (budget 512 w/ launch_bounds(256,1); expect ~400).
//   - Barrier (flag store + 64-lane poll + acquire fence) unchanged from the
//     passing Round-4 kernel. Poll backoff s_sleep(1).
//   - Fallback to f32 path if ws too small.

#define B_  64
#define T_  1024
#define U_  1024
#define E_  256
#define U3_ 3072

typedef __attribute__((ext_vector_type(8))) short short8;
typedef __attribute__((ext_vector_type(4))) float f32x4;

// ---- fragment offsets (in ushort units) ----
__device__ __forceinline__ size_t wrecOff(int cb,int nt,int ch,int sp){ return ((((size_t)cb*3+nt)*32+ch)*2+sp)*512; }
__device__ __forceinline__ size_t winOff (int cb,int nt,int ch,int sp){ return ((((size_t)cb*3+nt)*8 +ch)*2+sp)*512; }
__device__ __forceinline__ size_t hOff   (int mt,int ch,int sp){ return (((size_t)mt*32+ch)*2+sp)*512; }
__device__ __forceinline__ size_t eOff   (int mt,int ch,int sp){ return (((size_t)mt*8 +ch)*2+sp)*512; }

__device__ __forceinline__ void split_bf16(float v, unsigned short& hi, unsigned short& lo){
  union {float f; unsigned u;} a; a.f = v;
  unsigned r = a.u + 0x7FFFu + ((a.u>>16)&1u);
  hi = (unsigned short)(r>>16);
  union {unsigned u; float f;} hf; hf.u = ((unsigned)hi)<<16;
  float rem = v - hf.f;
  union {float f; unsigned u;} b; b.f = rem;
  unsigned r2 = b.u + 0x7FFFu + ((b.u>>16)&1u);
  lo = (unsigned short)(r2>>16);
}

// ---- once-per-call fragment builders ----
__global__ __launch_bounds__(256) void build_wfrag(
    const float* __restrict__ W, unsigned short* __restrict__ dst, int nch)
{
  const int blk = blockIdx.x;              // grid = 64*3*nch
  const int ch = blk % nch;
  const int nt = (blk/nch) % 3;
  const int cb = blk/(nch*3);
  const size_t base = ((((size_t)cb*3+nt)*nch+ch)*2)*512;
  for (int e = threadIdx.x; e < 512; e += 256){
    const int ln = e>>3, j = e&7;
    const int k = ch*32 + (ln>>4)*8 + j;
    const int c = nt*1024 + cb*16 + (ln&15);
    unsigned short hi, lo; split_bf16(W[(size_t)k*U3_ + c], hi, lo);
    dst[base + e]       = hi;
    dst[base + 512 + e] = lo;
  }
}

__global__ __launch_bounds__(256) void build_efrag(
    const int* __restrict__ x, const float* __restrict__ emb,
    unsigned short* __restrict__ eF)
{
  const int t = blockIdx.x;                // grid = 1024
  const size_t tbase = (size_t)t * 32768;
  for (int e = threadIdx.x; e < 16384; e += 256){
    const int mt = e >> 12; const int r = e & 4095;
    const int ch = r >> 9;  const int r2 = r & 511;
    const int ln = r2>>3, j = r2&7;
    const int b = mt*16 + (ln&15);
    const int k = ch*32 + (ln>>4)*8 + j;
    const int tok = x[b*T_ + t];
    unsigned short hi, lo; split_bf16(emb[(size_t)tok*E_ + k], hi, lo);
    const size_t off = tbase + (((size_t)mt*8+ch)*2)*512 + r2;
    eF[off]       = hi;
    eF[off + 512] = lo;
  }
}

__global__ __launch_bounds__(256) void build_hfrag(
    const float* __restrict__ h0, unsigned short* __restrict__ hF)
{
  for (int e = blockIdx.x*blockDim.x + threadIdx.x; e < 65536; e += gridDim.x*blockDim.x){
    const int mt = e >> 14; const int r = e & 16383;
    const int ch = r >> 9;  const int r2 = r & 511;
    const int ln = r2>>3, j = r2&7;
    const int b = mt*16 + (ln&15);
    const int k = ch*32 + (ln>>4)*8 + j;
    unsigned short hi, lo; split_bf16(h0[(size_t)b*U_ + k], hi, lo);
    const size_t off = (((size_t)mt*32+ch)*2)*512 + r2;
    hF[off]       = hi;
    hF[off + 512] = lo;
  }
}

__global__ void init_flags(unsigned* __restrict__ flags){
  flags[threadIdx.x] = 0u;                 // 256 flags (4 groups x 64 blocks)
}

// ---- input-projection partial (h-independent; overlaps barrier wait) ----
__device__ __forceinline__ void compute_accI(
    f32x4 (&accI)[3], const unsigned short* __restrict__ eFt,
    const short8 (&wih)[3][2], const short8 (&wil)[3][2],
    int mt, int kw, int ln)
{
  #pragma unroll
  for (int nt=0;nt<3;nt++) accI[nt] = (f32x4){0.f,0.f,0.f,0.f};
  short8 ah[2], al[2];
  #pragma unroll
  for (int ci=0;ci<2;ci++){
    const int ch = kw*2+ci;
    ah[ci] = *(const short8*)(eFt + eOff(mt,ch,0) + (size_t)ln*8);
    al[ci] = *(const short8*)(eFt + eOff(mt,ch,1) + (size_t)ln*8);
  }
  #pragma unroll
  for (int ci=0;ci<2;ci++){
    #pragma unroll
    for (int nt=0;nt<3;nt++)
      accI[nt] = __builtin_amdgcn_mfma_f32_16x16x32_bf16(ah[ci], wih[nt][ci], accI[nt], 0,0,0);
    #pragma unroll
    for (int nt=0;nt<3;nt++)
      accI[nt] = __builtin_amdgcn_mfma_f32_16x16x32_bf16(ah[ci], wil[nt][ci], accI[nt], 0,0,0);
    #pragma unroll
    for (int nt=0;nt<3;nt++)
      accI[nt] = __builtin_amdgcn_mfma_f32_16x16x32_bf16(al[ci], wih[nt][ci], accI[nt], 0,0,0);
  }
}

// ---- the persistent kernel ----
__global__ __launch_bounds__(256, 1) void gru_persistent(
    const unsigned short* __restrict__ WrecF, const unsigned short* __restrict__ WinF,
    unsigned short* __restrict__ hF, const unsigned short* __restrict__ eF,
    const float* __restrict__ init, const float* __restrict__ b_in,
    const float* __restrict__ b_rec, float* __restrict__ out,
    unsigned* __restrict__ flags)
{
  const int tid = (int)threadIdx.x;
  const int ln  = tid & 63;
  const int kw  = tid >> 6;                // k-split wave 0..3
  const int cb  = blockIdx.x & 63;         // column block (16 u x 3 gates)
  const int mt  = blockIdx.x >> 6;         // m-tile 0..3; barrier group

  // ---- weight fragments -> registers, resident for all T steps ----
  short8 wrh[3][8], wrl[3][8];             // W_rec hi/lo  (192 VGPRs)
  short8 wih[3][2], wil[3][2];             // W_in  hi/lo  ( 48 VGPRs)
  #pragma unroll
  for (int nt=0;nt<3;nt++){
    #pragma unroll
    for (int ci=0;ci<8;ci++){
      wrh[nt][ci] = *(const short8*)(WrecF + wrecOff(cb,nt,kw*8+ci,0) + (size_t)ln*8);
      wrl[nt][ci] = *(const short8*)(WrecF + wrecOff(cb,nt,kw*8+ci,1) + (size_t)ln*8);
    }
    #pragma unroll
    for (int ci=0;ci<2;ci++){
      wih[nt][ci] = *(const short8*)(WinF + winOff(cb,nt,kw*2+ci,0) + (size_t)ln*8);
      wil[nt][ci] = *(const short8*)(WinF + winOff(cb,nt,kw*2+ci,1) + (size_t)ln*8);
    }
  }
  // PIN: opaque def severs each value from its load -> compiler cannot
  // rematerialize inside the loop (asm"memory"/atomics otherwise block LICM,
  // which silently turned Round-4 into a reload-every-step kernel).
  #pragma unroll
  for (int nt=0;nt<3;nt++){
    #pragma unroll
    for (int ci=0;ci<8;ci++){
      asm volatile("" : "+v"(wrh[nt][ci]));
      asm volatile("" : "+v"(wrl[nt][ci]));
    }
    #pragma unroll
    for (int ci=0;ci<2;ci++){
      asm volatile("" : "+v"(wih[nt][ci]));
      asm volatile("" : "+v"(wil[nt][ci]));
    }
  }

  // ---- epilogue constants: this thread owns output (b, u) every step ----
  const int u   = cb*16 + (ln & 15);
  const int row = (ln >> 4)*4 + kw;        // acc reg index kw belongs to this wave
  const int b   = mt*16 + row;
  const float bz  = b_in[u]       + b_rec[u];
  const float brr = b_in[U_+u]    + b_rec[U_+u];
  const float bxh = b_in[2*U_+u];
  const float brh = b_rec[2*U_+u];
  float hp = init[(size_t)b*U_ + u];       // h_prev carried in-register
  const int chv = u>>5, jj = u&7;
  const int lnp = (b&15) + 16*((u>>3)&3);
  const size_t hstore0 = hOff(mt,chv,0) + (size_t)lnp*8 + jj;
  const size_t hstore1 = hOff(mt,chv,1) + (size_t)lnp*8 + jj;
  const size_t obase   = (size_t)b*((size_t)T_*U_) + u;
  unsigned* const fgrp = flags + mt*64;    // this group's 64 arrival flags

  __shared__ float red[4][64][25];         // k-split reduction, +1 pad

  f32x4 accI[3];
  compute_accI(accI, eF, wih, wil, mt, kw, ln);   // t = 0

  #pragma unroll 1
  for (int t = 0; t < T_; ++t){
    const unsigned short* hs = hF + (size_t)(t & 1)     * 131072;
    unsigned short*       hd = hF + (size_t)((t+1) & 1) * 131072;

    // ---- recurrent projection: this wave's 8 chunks of K=32 ----
    f32x4 accR[3];
    #pragma unroll
    for (int nt=0;nt<3;nt++) accR[nt] = (f32x4){0.f,0.f,0.f,0.f};
    short8 ah[8], al[8];
    #pragma unroll
    for (int ci=0;ci<8;ci++){              // issue all 16 loads, one round-trip
      const int ch = kw*8+ci;
      ah[ci] = *(const short8*)(hs + hOff(mt,ch,0) + (size_t)ln*8);
      al[ci] = *(const short8*)(hs + hOff(mt,ch,1) + (size_t)ln*8);
    }
    #pragma unroll
    for (int ci=0;ci<8;ci++){
      #pragma unroll
      for (int nt=0;nt<3;nt++)
        accR[nt] = __builtin_amdgcn_mfma_f32_16x16x32_bf16(ah[ci], wrh[nt][ci], accR[nt], 0,0,0);
      #pragma unroll
      for (int nt=0;nt<3;nt++)
        accR[nt] = __builtin_amdgcn_mfma_f32_16x16x32_bf16(ah[ci], wrl[nt][ci], accR[nt], 0,0,0);
      #pragma unroll
      for (int nt=0;nt<3;nt++)
        accR[nt] = __builtin_amdgcn_mfma_f32_16x16x32_bf16(al[ci], wrh[nt][ci], accR[nt], 0,0,0);
    }

    // ---- k-split reduction across the 4 waves via LDS ----
    #pragma unroll
    for (int nt=0;nt<3;nt++)
      #pragma unroll
      for (int r2=0;r2<4;r2++){
        red[kw][ln][nt*4+r2]      = accR[nt][r2];
        red[kw][ln][12 + nt*4+r2] = accI[nt][r2];
      }
    __syncthreads();
    float Rz=0.f,Rr=0.f,Rh=0.f,Iz=0.f,Ir=0.f,Ih=0.f;
    #pragma unroll
    for (int k2=0;k2<4;k2++){
      Rz += red[k2][ln][kw];
      Rr += red[k2][ln][4+kw];
      Rh += red[k2][ln][8+kw];
      Iz += red[k2][ln][12+kw];
      Ir += red[k2][ln][16+kw];
      Ih += red[k2][ln][20+kw];
    }

    // ---- gates: exactly one output per thread ----
    const float z  = 1.f/(1.f+__expf(-(Rz+Iz+bz)));
    const float r  = 1.f/(1.f+__expf(-(Rr+Ir+brr)));
    const float ta = Ih + bxh + r*(Rh + brh);
    const float e2 = __expf(2.f*ta);
    const float hh = 1.f - 2.f/(e2+1.f);   // tanh(ta)
    const float hn = z*hp + (1.f-z)*hh;
    hp = hn;

    // ---- h state: coherent (sc1) stores -> visible at LLC once vmcnt=0 ----
    unsigned short hi, lo; split_bf16(hn, hi, lo);
    __hip_atomic_store(hd + hstore0, hi, __ATOMIC_RELAXED, __HIP_MEMORY_SCOPE_AGENT);
    __hip_atomic_store(hd + hstore1, lo, __ATOMIC_RELAXED, __HIP_MEMORY_SCOPE_AGENT);

    if (t == T_-1){
      out[obase + (size_t)t*U_] = hn;
      out[(size_t)B_*T_*U_ + (size_t)b*U_ + u] = hn;
      break;
    }

    asm volatile("s_waitcnt vmcnt(0)" ::: "memory");  // h stores at LLC
    __syncthreads();                        // all waves drained; red reusable

    // ---- arrival: one 4B flag store per block, distinct addresses ----
    if (tid == 0)
      __hip_atomic_store(&fgrp[cb], (unsigned)(t+1), __ATOMIC_RELAXED, __HIP_MEMORY_SCOPE_AGENT);
    __builtin_amdgcn_sched_barrier(0);      // don't let the store sink

    // off-critical-path work in the barrier shadow:
    __builtin_nontemporal_store(hn, &out[obase + (size_t)t*U_]);
    compute_accI(accI, eF + (size_t)(t+1)*32768, wih, wil, mt, kw, ln);

    // ---- wait: wave 0 polls all 64 flags with one 64-lane load ----
    if (tid < 64){
      const unsigned tgt = (unsigned)(t+1);
      while (true){
        const unsigned f = __hip_atomic_load(&fgrp[ln], __ATOMIC_RELAXED, __HIP_MEMORY_SCOPE_AGENT);
        if (__all(f >= tgt)) break;
        __builtin_amdgcn_s_sleep(1);
      }
    }
    __syncthreads();
    __builtin_amdgcn_fence(__ATOMIC_ACQUIRE, "agent");  // inv L1/L2 before h reads
  }
}

// ================= Round-0 f32 fallback path =================
__global__ __launch_bounds__(256) void transpose_f32(
    const float* __restrict__ in, float* __restrict__ out, int R, int C)
{
  __shared__ float tile[32][33];
  const int bc = blockIdx.x * 32;
  const int br = blockIdx.y * 32;
  const int tx = threadIdx.x & 31;
  const int ty = threadIdx.x >> 5;
#pragma unroll
  for (int i = 0; i < 32; i += 8)
    tile[ty + i][tx] = in[(size_t)(br + ty + i) * C + (bc + tx)];
  __syncthreads();
#pragma unroll
  for (int i = 0; i < 32; i += 8)
    out[(size_t)(bc + ty + i) * R + (br + tx)] = tile[tx][ty + i];
}

template<bool USE_WT>
__global__ __launch_bounds__(512) void gru_step(
    const float* __restrict__ h_src, int h_stride,
    const int*   __restrict__ x, int t,
    const float* __restrict__ emb,
    const float* __restrict__ Wrec,
    const float* __restrict__ WrecT,
    const float* __restrict__ Win,
    const float* __restrict__ WinT,
    const float* __restrict__ b_in,
    const float* __restrict__ b_rec,
    float* __restrict__ out)
{
  __shared__ float sh[64 * 129];
  const int tid = (int)threadIdx.x;
  const int b   = tid & 63;
  const int j   = tid >> 6;
  const int uj  = j & 3;
  const int kh  = j >> 2;
  const int u   = blockIdx.x * 4 + uj;

  float az = 0.f, ar = 0.f, arh = 0.f, axh = 0.f;

  for (int kc = 0; kc < U_; kc += 128) {
#pragma unroll
    for (int l = tid; l < 2048; l += 512) {
      const int row = l >> 5, c4 = l & 31;
      const int c4r = (c4 + row) & 31;
      const float4 v = *reinterpret_cast<const float4*>(
          h_src + (size_t)row * h_stride + (kc + c4r * 4));
      float* d = &sh[row * 129 + c4r * 4];
      d[0] = v.x; d[1] = v.y; d[2] = v.z; d[3] = v.w;
    }
    __syncthreads();
    const float* hrow = &sh[b * 129 + kh * 64];
    const int kb = kc + kh * 64;
    if (USE_WT) {
      const float4* wz = reinterpret_cast<const float4*>(WrecT + (size_t)u * U_ + kb);
      const float4* wr = reinterpret_cast<const float4*>(WrecT + (size_t)(U_ + u) * U_ + kb);
      const float4* wh = reinterpret_cast<const float4*>(WrecT + (size_t)(2 * U_ + u) * U_ + kb);
#pragma unroll 8
      for (int k4 = 0; k4 < 16; ++k4) {
        const float4 z4 = wz[k4], r4 = wr[k4], h4 = wh[k4];
        const float h0 = hrow[k4*4+0], h1 = hrow[k4*4+1], h2 = hrow[k4*4+2], h3 = hrow[k4*4+3];
        az  += h0*z4.x; az  += h1*z4.y; az  += h2*z4.z; az  += h3*z4.w;
        ar  += h0*r4.x; ar  += h1*r4.y; ar  += h2*r4.z; ar  += h3*r4.w;
        arh += h0*h4.x; arh += h1*h4.y; arh += h2*h4.z; arh += h3*h4.w;
      }
    } else {
#pragma unroll 4
      for (int k = 0; k < 64; ++k) {
        const float hv = hrow[k];
        const size_t roff = (size_t)(kb + k) * U3_;
        az  += hv * Wrec[roff + u];
        ar  += hv * Wrec[roff + U_ + u];
        arh += hv * Wrec[roff + 2 * U_ + u];
      }
    }
    __syncthreads();
  }

  for (int kc = 0; kc < E_; kc += 128) {
#pragma unroll
    for (int l = tid; l < 2048; l += 512) {
      const int row = l >> 5, c4 = l & 31;
      const int c4r = (c4 + row) & 31;
      const int tok = x[row * T_ + t];
      const float4 v = *reinterpret_cast<const float4*>(
          emb + (size_t)tok * E_ + (kc + c4r * 4));
      float* d = &sh[row * 129 + c4r * 4];
      d[0] = v.x; d[1] = v.y; d[2] = v.z; d[3] = v.w;
    }
    __syncthreads();
    const float* erow = &sh[b * 129 + kh * 64];
    const int kb = kc + kh * 64;
    if (USE_WT) {
      const float4* wz = reinterpret_cast<const float4*>(WinT + (size_t)u * E_ + kb);
      const float4* wr = reinterpret_cast<const float4*>(WinT + (size_t)(U_ + u) * E_ + kb);
      const float4* wh = reinterpret_cast<const float4*>(WinT + (size_t)(2 * U_ + u) * E_ + kb);
#pragma unroll 8
      for (int k4 = 0; k4 < 16; ++k4) {
        const float4 z4 = wz[k4], r4 = wr[k4], h4 = wh[k4];
        const float h0 = erow[k4*4+0], h1 = erow[k4*4+1], h2 = erow[k4*4+2], h3 = erow[k4*4+3];
        az  += h0*z4.x; az  += h1*z4.y; az  += h2*z4.z; az  += h3*z4.w;
        ar  += h0*r4.x; ar  += h1*r4.y; ar  += h2*r4.z; ar  += h3*r4.w;
        axh += h0*h4.x; axh += h1*h4.y; axh += h2*h4.z; axh += h3*h4.w;
      }
    } else {
#pragma unroll 4
      for (int k = 0; k < 64; ++k) {
        const float ev = erow[k];
        const size_t roff = (size_t)(kb + k) * U3_;
        az  += ev * Win[roff + u];
        ar  += ev * Win[roff + U_ + u];
        axh += ev * Win[roff + 2 * U_ + u];
      }
    }
    __syncthreads();
  }

  if (kh == 1) {
    sh[(0*4+uj)*64 + b] = az;
    sh[(1*4+uj)*64 + b] = ar;
    sh[(2*4+uj)*64 + b] = arh;
    sh[(3*4+uj)*64 + b] = axh;
  }
  __syncthreads();
  if (kh == 0) {
    az  += sh[(0*4+uj)*64 + b];
    ar  += sh[(1*4+uj)*64 + b];
    arh += sh[(2*4+uj)*64 + b];
    axh += sh[(3*4+uj)*64 + b];

    const float bz  = b_in[u]          + b_rec[u];
    const float brr = b_in[U_ + u]     + b_rec[U_ + u];
    const float bxh = b_in[2 * U_ + u];
    const float brh = b_rec[2 * U_ + u];

    const float z  = 1.f / (1.f + expf(-(az + bz)));
    const float r  = 1.f / (1.f + expf(-(ar + brr)));
    const float hh = tanhf(axh + bxh + r * (arh + brh));
    const float hp = h_src[(size_t)b * h_stride + u];
    const float hn = z * hp + (1.f - z) * hh;

    out[(size_t)b * ((size_t)T_ * U_) + (size_t)t * U_ + u] = hn;
    if (t == T_ - 1)
      out[(size_t)B_ * T_ * U_ + (size_t)b * U_ + u] = hn;
  }
}

extern "C" void kernel_launch(void* const* d_in, const int* in_sizes, int n_in,
                              void* d_out, int out_size, void* d_ws, size_t ws_size,
                              hipStream_t stream) {
  (void)in_sizes; (void)n_in; (void)out_size;
  const int*   x     = (const int*)  d_in[0];
  const float* init  = (const float*)d_in[1];
  const float* emb   = (const float*)d_in[2];
  const float* Win   = (const float*)d_in[3];
  const float* Wrec  = (const float*)d_in[4];
  const float* b_in  = (const float*)d_in[5];
  const float* b_rec = (const float*)d_in[6];
  float* out = (float*)d_out;

  // ---- persistent-MFMA path ws layout (ushort units) ----
  const size_t nWrecF = 6291456;    // 64*3*32*2*512
  const size_t nWinF  = 1572864;    // 64*3*8*2*512
  const size_t nhF    = 262144;     // 2 * 131072
  const size_t neF    = 33554432;   // 1024 * 32768
  const size_t needMF = (nWrecF + nWinF + nhF + neF) * sizeof(unsigned short);

  if (d_ws != nullptr && ws_size >= needMF + 4096) {
    unsigned short* WrecF = (unsigned short*)d_ws;
    unsigned short* WinF  = WrecF + nWrecF;
    unsigned short* hF    = WinF  + nWinF;
    unsigned short* eF    = hF    + nhF;
    unsigned*       flags = (unsigned*)((char*)d_ws + needMF);

    build_wfrag<<<64*3*32, 256, 0, stream>>>(Wrec, WrecF, 32);
    build_wfrag<<<64*3*8,  256, 0, stream>>>(Win,  WinF,  8);
    build_hfrag<<<256, 256, 0, stream>>>(init, hF);      // parity 0
    build_efrag<<<1024, 256, 0, stream>>>(x, emb, eF);
    init_flags<<<1, 256, 0, stream>>>(flags);

    gru_persistent<<<256, 256, 0, stream>>>(WrecF, WinF, hF, eF,
        init, b_in, b_rec, out, flags);
    return;
  }

  // ---- fallback: Round-0 f32 path ----
  float* WrecT = (float*)d_ws;
  float* WinT  = WrecT + (size_t)U3_ * U_;
  const size_t needT = ((size_t)U3_ * U_ + (size_t)U3_ * E_) * sizeof(float);
  const bool useWT = (d_ws != nullptr) && (ws_size >= needT);

  if (useWT) {
    transpose_f32<<<dim3(U3_/32, U_/32), 256, 0, stream>>>(Wrec, WrecT, U_, U3_);
    transpose_f32<<<dim3(U3_/32, E_/32), 256, 0, stream>>>(Win,  WinT,  E_, U3_);
    for (int t = 0; t < T_; ++t) {
      const float* hsrc = (t == 0) ? init : (out + (size_t)(t-1) * U_);
      const int hs = (t == 0) ? U_ : T_ * U_;
      gru_step<true><<<256, 512, 0, stream>>>(hsrc, hs, x, t, emb,
          Wrec, WrecT, Win, WinT, b_in, b_rec, out);
    }
  } else {
    for (int t = 0; t < T_; ++t) {
      const float* hsrc = (t == 0) ? init : (out + (size_t)(t-1) * U_);
      const int hs = (t == 0) ? U_ : T_ * U_;
      gru_step<false><<<256, 512, 0, stream>>>(hsrc, hs, x, t, emb,
          Wrec, WrecT, Win, WinT, b_in, b_rec, out);
    }
  }
}

// Round 4
// 11257.639 us; speedup vs baseline: 1.0124x; 1.0124x over previous
//
#include <hip/hip_runtime.h>
#include <hip/hip_bf16.h>
#include <math.h>

// GRU encoder: B=64, T=1024, V=32000, E=256, U=1024, gates [z,r,h], reset_after.
// Round 6: persistent kernel + cheap barrier + AGPR-PINNED weights.
//   - Round-5 post-mortem: "+v" pin did NOT give register residency
//     (VGPR_Count=168, FETCH_SIZE unchanged, dur unchanged) -> allocator
//     spilled the pinned values to scratch; scratch reload == LLC reload.
//   - Fix: pin weight fragments into AGPRs ("+a" constraint). gfx950 unified
//     file: 512 regs/wave at launch_bounds(256,1); weights=240 AGPR + ~170
//     arch VGPR = 410 < 512. MFMA reads B operands from AGPR directly (AV
//     operand classes); AGPRs have zero competing pressure and are immune to
//     the per-step acquire-fence cache invalidation.
//   - Everything else identical to the passing Round-5 kernel.
//   - Fallback to f32 path if ws too small.

#define B_  64
#define T_  1024
#define U_  1024
#define E_  256
#define U3_ 3072

typedef __attribute__((ext_vector_type(8))) short short8;
typedef __attribute__((ext_vector_type(4))) float f32x4;

// ---- fragment offsets (in ushort units) ----
__device__ __forceinline__ size_t wrecOff(int cb,int nt,int ch,int sp){ return ((((size_t)cb*3+nt)*32+ch)*2+sp)*512; }
__device__ __forceinline__ size_t winOff (int cb,int nt,int ch,int sp){ return ((((size_t)cb*3+nt)*8 +ch)*2+sp)*512; }
__device__ __forceinline__ size_t hOff   (int mt,int ch,int sp){ return (((size_t)mt*32+ch)*2+sp)*512; }
__device__ __forceinline__ size_t eOff   (int mt,int ch,int sp){ return (((size_t)mt*8 +ch)*2+sp)*512; }

__device__ __forceinline__ void split_bf16(float v, unsigned short& hi, unsigned short& lo){
  union {float f; unsigned u;} a; a.f = v;
  unsigned r = a.u + 0x7FFFu + ((a.u>>16)&1u);
  hi = (unsigned short)(r>>16);
  union {unsigned u; float f;} hf; hf.u = ((unsigned)hi)<<16;
  float rem = v - hf.f;
  union {float f; unsigned u;} b; b.f = rem;
  unsigned r2 = b.u + 0x7FFFu + ((b.u>>16)&1u);
  lo = (unsigned short)(r2>>16);
}

// ---- once-per-call fragment builders ----
__global__ __launch_bounds__(256) void build_wfrag(
    const float* __restrict__ W, unsigned short* __restrict__ dst, int nch)
{
  const int blk = blockIdx.x;              // grid = 64*3*nch
  const int ch = blk % nch;
  const int nt = (blk/nch) % 3;
  const int cb = blk/(nch*3);
  const size_t base = ((((size_t)cb*3+nt)*nch+ch)*2)*512;
  for (int e = threadIdx.x; e < 512; e += 256){
    const int ln = e>>3, j = e&7;
    const int k = ch*32 + (ln>>4)*8 + j;
    const int c = nt*1024 + cb*16 + (ln&15);
    unsigned short hi, lo; split_bf16(W[(size_t)k*U3_ + c], hi, lo);
    dst[base + e]       = hi;
    dst[base + 512 + e] = lo;
  }
}

__global__ __launch_bounds__(256) void build_efrag(
    const int* __restrict__ x, const float* __restrict__ emb,
    unsigned short* __restrict__ eF)
{
  const int t = blockIdx.x;                // grid = 1024
  const size_t tbase = (size_t)t * 32768;
  for (int e = threadIdx.x; e < 16384; e += 256){
    const int mt = e >> 12; const int r = e & 4095;
    const int ch = r >> 9;  const int r2 = r & 511;
    const int ln = r2>>3, j = r2&7;
    const int b = mt*16 + (ln&15);
    const int k = ch*32 + (ln>>4)*8 + j;
    const int tok = x[b*T_ + t];
    unsigned short hi, lo; split_bf16(emb[(size_t)tok*E_ + k], hi, lo);
    const size_t off = tbase + (((size_t)mt*8+ch)*2)*512 + r2;
    eF[off]       = hi;
    eF[off + 512] = lo;
  }
}

__global__ __launch_bounds__(256) void build_hfrag(
    const float* __restrict__ h0, unsigned short* __restrict__ hF)
{
  for (int e = blockIdx.x*blockDim.x + threadIdx.x; e < 65536; e += gridDim.x*blockDim.x){
    const int mt = e >> 14; const int r = e & 16383;
    const int ch = r >> 9;  const int r2 = r & 511;
    const int ln = r2>>3, j = r2&7;
    const int b = mt*16 + (ln&15);
    const int k = ch*32 + (ln>>4)*8 + j;
    unsigned short hi, lo; split_bf16(h0[(size_t)b*U_ + k], hi, lo);
    const size_t off = (((size_t)mt*32+ch)*2)*512 + r2;
    hF[off]       = hi;
    hF[off + 512] = lo;
  }
}

__global__ void init_flags(unsigned* __restrict__ flags){
  flags[threadIdx.x] = 0u;                 // 256 flags (4 groups x 64 blocks)
}

// ---- input-projection partial (h-independent; overlaps barrier wait) ----
__device__ __forceinline__ void compute_accI(
    f32x4 (&accI)[3], const unsigned short* __restrict__ eFt,
    const short8 (&wih)[3][2], const short8 (&wil)[3][2],
    int mt, int kw, int ln)
{
  #pragma unroll
  for (int nt=0;nt<3;nt++) accI[nt] = (f32x4){0.f,0.f,0.f,0.f};
  short8 ah[2], al[2];
  #pragma unroll
  for (int ci=0;ci<2;ci++){
    const int ch = kw*2+ci;
    ah[ci] = *(const short8*)(eFt + eOff(mt,ch,0) + (size_t)ln*8);
    al[ci] = *(const short8*)(eFt + eOff(mt,ch,1) + (size_t)ln*8);
  }
  #pragma unroll
  for (int ci=0;ci<2;ci++){
    #pragma unroll
    for (int nt=0;nt<3;nt++)
      accI[nt] = __builtin_amdgcn_mfma_f32_16x16x32_bf16(ah[ci], wih[nt][ci], accI[nt], 0,0,0);
    #pragma unroll
    for (int nt=0;nt<3;nt++)
      accI[nt] = __builtin_amdgcn_mfma_f32_16x16x32_bf16(ah[ci], wil[nt][ci], accI[nt], 0,0,0);
    #pragma unroll
    for (int nt=0;nt<3;nt++)
      accI[nt] = __builtin_amdgcn_mfma_f32_16x16x32_bf16(al[ci], wih[nt][ci], accI[nt], 0,0,0);
  }
}

// ---- the persistent kernel ----
__global__ __launch_bounds__(256, 1) void gru_persistent(
    const unsigned short* __restrict__ WrecF, const unsigned short* __restrict__ WinF,
    unsigned short* __restrict__ hF, const unsigned short* __restrict__ eF,
    const float* __restrict__ init, const float* __restrict__ b_in,
    const float* __restrict__ b_rec, float* __restrict__ out,
    unsigned* __restrict__ flags)
{
  const int tid = (int)threadIdx.x;
  const int ln  = tid & 63;
  const int kw  = tid >> 6;                // k-split wave 0..3
  const int cb  = blockIdx.x & 63;         // column block (16 u x 3 gates)
  const int mt  = blockIdx.x >> 6;         // m-tile 0..3; barrier group

  // ---- weight fragments -> registers, resident for all T steps ----
  short8 wrh[3][8], wrl[3][8];             // W_rec hi/lo  (192 regs)
  short8 wih[3][2], wil[3][2];             // W_in  hi/lo  ( 48 regs)
  #pragma unroll
  for (int nt=0;nt<3;nt++){
    #pragma unroll
    for (int ci=0;ci<8;ci++){
      wrh[nt][ci] = *(const short8*)(WrecF + wrecOff(cb,nt,kw*8+ci,0) + (size_t)ln*8);
      wrl[nt][ci] = *(const short8*)(WrecF + wrecOff(cb,nt,kw*8+ci,1) + (size_t)ln*8);
    }
    #pragma unroll
    for (int ci=0;ci<2;ci++){
      wih[nt][ci] = *(const short8*)(WinF + winOff(cb,nt,kw*2+ci,0) + (size_t)ln*8);
      wil[nt][ci] = *(const short8*)(WinF + winOff(cb,nt,kw*2+ci,1) + (size_t)ln*8);
    }
  }
  // PIN into AGPRs: "+a" forces the AGPR register class (zero competing
  // pressure; MFMA consumes AGPR B-operands directly; immune to the per-step
  // cache invalidation). Round-5's "+v" pin was spilled to scratch by the
  // allocator -- same reload cost as before, no win.
  #pragma unroll
  for (int nt=0;nt<3;nt++){
    #pragma unroll
    for (int ci=0;ci<8;ci++){
      asm volatile("" : "+a"(wrh[nt][ci]));
      asm volatile("" : "+a"(wrl[nt][ci]));
    }
    #pragma unroll
    for (int ci=0;ci<2;ci++){
      asm volatile("" : "+a"(wih[nt][ci]));
      asm volatile("" : "+a"(wil[nt][ci]));
    }
  }

  // ---- epilogue constants: this thread owns output (b, u) every step ----
  const int u   = cb*16 + (ln & 15);
  const int row = (ln >> 4)*4 + kw;        // acc reg index kw belongs to this wave
  const int b   = mt*16 + row;
  const float bz  = b_in[u]       + b_rec[u];
  const float brr = b_in[U_+u]    + b_rec[U_+u];
  const float bxh = b_in[2*U_+u];
  const float brh = b_rec[2*U_+u];
  float hp = init[(size_t)b*U_ + u];       // h_prev carried in-register
  const int chv = u>>5, jj = u&7;
  const int lnp = (b&15) + 16*((u>>3)&3);
  const size_t hstore0 = hOff(mt,chv,0) + (size_t)lnp*8 + jj;
  const size_t hstore1 = hOff(mt,chv,1) + (size_t)lnp*8 + jj;
  const size_t obase   = (size_t)b*((size_t)T_*U_) + u;
  unsigned* const fgrp = flags + mt*64;    // this group's 64 arrival flags

  __shared__ float red[4][64][25];         // k-split reduction, +1 pad

  f32x4 accI[3];
  compute_accI(accI, eF, wih, wil, mt, kw, ln);   // t = 0

  #pragma unroll 1
  for (int t = 0; t < T_; ++t){
    const unsigned short* hs = hF + (size_t)(t & 1)     * 131072;
    unsigned short*       hd = hF + (size_t)((t+1) & 1) * 131072;

    // ---- recurrent projection: this wave's 8 chunks of K=32 ----
    f32x4 accR[3];
    #pragma unroll
    for (int nt=0;nt<3;nt++) accR[nt] = (f32x4){0.f,0.f,0.f,0.f};
    short8 ah[8], al[8];
    #pragma unroll
    for (int ci=0;ci<8;ci++){              // issue all 16 loads, one round-trip
      const int ch = kw*8+ci;
      ah[ci] = *(const short8*)(hs + hOff(mt,ch,0) + (size_t)ln*8);
      al[ci] = *(const short8*)(hs + hOff(mt,ch,1) + (size_t)ln*8);
    }
    #pragma unroll
    for (int ci=0;ci<8;ci++){
      #pragma unroll
      for (int nt=0;nt<3;nt++)
        accR[nt] = __builtin_amdgcn_mfma_f32_16x16x32_bf16(ah[ci], wrh[nt][ci], accR[nt], 0,0,0);
      #pragma unroll
      for (int nt=0;nt<3;nt++)
        accR[nt] = __builtin_amdgcn_mfma_f32_16x16x32_bf16(ah[ci], wrl[nt][ci], accR[nt], 0,0,0);
      #pragma unroll
      for (int nt=0;nt<3;nt++)
        accR[nt] = __builtin_amdgcn_mfma_f32_16x16x32_bf16(al[ci], wrh[nt][ci], accR[nt], 0,0,0);
    }

    // ---- k-split reduction across the 4 waves via LDS ----
    #pragma unroll
    for (int nt=0;nt<3;nt++)
      #pragma unroll
      for (int r2=0;r2<4;r2++){
        red[kw][ln][nt*4+r2]      = accR[nt][r2];
        red[kw][ln][12 + nt*4+r2] = accI[nt][r2];
      }
    __syncthreads();
    float Rz=0.f,Rr=0.f,Rh=0.f,Iz=0.f,Ir=0.f,Ih=0.f;
    #pragma unroll
    for (int k2=0;k2<4;k2++){
      Rz += red[k2][ln][kw];
      Rr += red[k2][ln][4+kw];
      Rh += red[k2][ln][8+kw];
      Iz += red[k2][ln][12+kw];
      Ir += red[k2][ln][16+kw];
      Ih += red[k2][ln][20+kw];
    }

    // ---- gates: exactly one output per thread ----
    const float z  = 1.f/(1.f+__expf(-(Rz+Iz+bz)));
    const float r  = 1.f/(1.f+__expf(-(Rr+Ir+brr)));
    const float ta = Ih + bxh + r*(Rh + brh);
    const float e2 = __expf(2.f*ta);
    const float hh = 1.f - 2.f/(e2+1.f);   // tanh(ta)
    const float hn = z*hp + (1.f-z)*hh;
    hp = hn;

    // ---- h state: coherent (sc1) stores -> visible at LLC once vmcnt=0 ----
    unsigned short hi, lo; split_bf16(hn, hi, lo);
    __hip_atomic_store(hd + hstore0, hi, __ATOMIC_RELAXED, __HIP_MEMORY_SCOPE_AGENT);
    __hip_atomic_store(hd + hstore1, lo, __ATOMIC_RELAXED, __HIP_MEMORY_SCOPE_AGENT);

    if (t == T_-1){
      out[obase + (size_t)t*U_] = hn;
      out[(size_t)B_*T_*U_ + (size_t)b*U_ + u] = hn;
      break;
    }

    asm volatile("s_waitcnt vmcnt(0)" ::: "memory");  // h stores at LLC
    __syncthreads();                        // all waves drained; red reusable

    // ---- arrival: one 4B flag store per block, distinct addresses ----
    if (tid == 0)
      __hip_atomic_store(&fgrp[cb], (unsigned)(t+1), __ATOMIC_RELAXED, __HIP_MEMORY_SCOPE_AGENT);
    __builtin_amdgcn_sched_barrier(0);      // don't let the store sink

    // off-critical-path work in the barrier shadow:
    __builtin_nontemporal_store(hn, &out[obase + (size_t)t*U_]);
    compute_accI(accI, eF + (size_t)(t+1)*32768, wih, wil, mt, kw, ln);

    // ---- wait: wave 0 polls all 64 flags with one 64-lane load ----
    if (tid < 64){
      const unsigned tgt = (unsigned)(t+1);
      while (true){
        const unsigned f = __hip_atomic_load(&fgrp[ln], __ATOMIC_RELAXED, __HIP_MEMORY_SCOPE_AGENT);
        if (__all(f >= tgt)) break;
        __builtin_amdgcn_s_sleep(1);
      }
    }
    __syncthreads();
    __builtin_amdgcn_fence(__ATOMIC_ACQUIRE, "agent");  // inv L1/L2 before h reads
  }
}

// ================= Round-0 f32 fallback path =================
__global__ __launch_bounds__(256) void transpose_f32(
    const float* __restrict__ in, float* __restrict__ out, int R, int C)
{
  __shared__ float tile[32][33];
  const int bc = blockIdx.x * 32;
  const int br = blockIdx.y * 32;
  const int tx = threadIdx.x & 31;
  const int ty = threadIdx.x >> 5;
#pragma unroll
  for (int i = 0; i < 32; i += 8)
    tile[ty + i][tx] = in[(size_t)(br + ty + i) * C + (bc + tx)];
  __syncthreads();
#pragma unroll
  for (int i = 0; i < 32; i += 8)
    out[(size_t)(bc + ty + i) * R + (br + tx)] = tile[tx][ty + i];
}

template<bool USE_WT>
__global__ __launch_bounds__(512) void gru_step(
    const float* __restrict__ h_src, int h_stride,
    const int*   __restrict__ x, int t,
    const float* __restrict__ emb,
    const float* __restrict__ Wrec,
    const float* __restrict__ WrecT,
    const float* __restrict__ Win,
    const float* __restrict__ WinT,
    const float* __restrict__ b_in,
    const float* __restrict__ b_rec,
    float* __restrict__ out)
{
  __shared__ float sh[64 * 129];
  const int tid = (int)threadIdx.x;
  const int b   = tid & 63;
  const int j   = tid >> 6;
  const int uj  = j & 3;
  const int kh  = j >> 2;
  const int u   = blockIdx.x * 4 + uj;

  float az = 0.f, ar = 0.f, arh = 0.f, axh = 0.f;

  for (int kc = 0; kc < U_; kc += 128) {
#pragma unroll
    for (int l = tid; l < 2048; l += 512) {
      const int row = l >> 5, c4 = l & 31;
      const int c4r = (c4 + row) & 31;
      const float4 v = *reinterpret_cast<const float4*>(
          h_src + (size_t)row * h_stride + (kc + c4r * 4));
      float* d = &sh[row * 129 + c4r * 4];
      d[0] = v.x; d[1] = v.y; d[2] = v.z; d[3] = v.w;
    }
    __syncthreads();
    const float* hrow = &sh[b * 129 + kh * 64];
    const int kb = kc + kh * 64;
    if (USE_WT) {
      const float4* wz = reinterpret_cast<const float4*>(WrecT + (size_t)u * U_ + kb);
      const float4* wr = reinterpret_cast<const float4*>(WrecT + (size_t)(U_ + u) * U_ + kb);
      const float4* wh = reinterpret_cast<const float4*>(WrecT + (size_t)(2 * U_ + u) * U_ + kb);
#pragma unroll 8
      for (int k4 = 0; k4 < 16; ++k4) {
        const float4 z4 = wz[k4], r4 = wr[k4], h4 = wh[k4];
        const float h0 = hrow[k4*4+0], h1 = hrow[k4*4+1], h2 = hrow[k4*4+2], h3 = hrow[k4*4+3];
        az  += h0*z4.x; az  += h1*z4.y; az  += h2*z4.z; az  += h3*z4.w;
        ar  += h0*r4.x; ar  += h1*r4.y; ar  += h2*r4.z; ar  += h3*r4.w;
        arh += h0*h4.x; arh += h1*h4.y; arh += h2*h4.z; arh += h3*h4.w;
      }
    } else {
#pragma unroll 4
      for (int k = 0; k < 64; ++k) {
        const float hv = hrow[k];
        const size_t roff = (size_t)(kb + k) * U3_;
        az  += hv * Wrec[roff + u];
        ar  += hv * Wrec[roff + U_ + u];
        arh += hv * Wrec[roff + 2 * U_ + u];
      }
    }
    __syncthreads();
  }

  for (int kc = 0; kc < E_; kc += 128) {
#pragma unroll
    for (int l = tid; l < 2048; l += 512) {
      const int row = l >> 5, c4 = l & 31;
      const int c4r = (c4 + row) & 31;
      const int tok = x[row * T_ + t];
      const float4 v = *reinterpret_cast<const float4*>(
          emb + (size_t)tok * E_ + (kc + c4r * 4));
      float* d = &sh[row * 129 + c4r * 4];
      d[0] = v.x; d[1] = v.y; d[2] = v.z; d[3] = v.w;
    }
    __syncthreads();
    const float* erow = &sh[b * 129 + kh * 64];
    const int kb = kc + kh * 64;
    if (USE_WT) {
      const float4* wz = reinterpret_cast<const float4*>(WinT + (size_t)u * E_ + kb);
      const float4* wr = reinterpret_cast<const float4*>(WinT + (size_t)(U_ + u) * E_ + kb);
      const float4* wh = reinterpret_cast<const float4*>(WinT + (size_t)(2 * U_ + u) * E_ + kb);
#pragma unroll 8
      for (int k4 = 0; k4 < 16; ++k4) {
        const float4 z4 = wz[k4], r4 = wr[k4], h4 = wh[k4];
        const float h0 = erow[k4*4+0], h1 = erow[k4*4+1], h2 = erow[k4*4+2], h3 = erow[k4*4+3];
        az  += h0*z4.x; az  += h1*z4.y; az  += h2*z4.z; az  += h3*z4.w;
        ar  += h0*r4.x; ar  += h1*r4.y; ar  += h2*r4.z; ar  += h3*r4.w;
        axh += h0*h4.x; axh += h1*h4.y; axh += h2*h4.z; axh += h3*h4.w;
      }
    } else {
#pragma unroll 4
      for (int k = 0; k < 64; ++k) {
        const float ev = erow[k];
        const size_t roff = (size_t)(kb + k) * U3_;
        az  += ev * Win[roff + u];
        ar  += ev * Win[roff + U_ + u];
        axh += ev * Win[roff + 2 * U_ + u];
      }
    }
    __syncthreads();
  }

  if (kh == 1) {
    sh[(0*4+uj)*64 + b] = az;
    sh[(1*4+uj)*64 + b] = ar;
    sh[(2*4+uj)*64 + b] = arh;
    sh[(3*4+uj)*64 + b] = axh;
  }
  __syncthreads();
  if (kh == 0) {
    az  += sh[(0*4+uj)*64 + b];
    ar  += sh[(1*4+uj)*64 + b];
    arh += sh[(2*4+uj)*64 + b];
    axh += sh[(3*4+uj)*64 + b];

    const float bz  = b_in[u]          + b_rec[u];
    const float brr = b_in[U_ + u]     + b_rec[U_ + u];
    const float bxh = b_in[2 * U_ + u];
    const float brh = b_rec[2 * U_ + u];

    const float z  = 1.f / (1.f + expf(-(az + bz)));
    const float r  = 1.f / (1.f + expf(-(ar + brr)));
    const float hh = tanhf(axh + bxh + r * (arh + brh));
    const float hp = h_src[(size_t)b * h_stride + u];
    const float hn = z * hp + (1.f - z) * hh;

    out[(size_t)b * ((size_t)T_ * U_) + (size_t)t * U_ + u] = hn;
    if (t == T_ - 1)
      out[(size_t)B_ * T_ * U_ + (size_t)b * U_ + u] = hn;
  }
}

extern "C" void kernel_launch(void* const* d_in, const int* in_sizes, int n_in,
                              void* d_out, int out_size, void* d_ws, size_t ws_size,
                              hipStream_t stream) {
  (void)in_sizes; (void)n_in; (void)out_size;
  const int*   x     = (const int*)  d_in[0];
  const float* init  = (const float*)d_in[1];
  const float* emb   = (const float*)d_in[2];
  const float* Win   = (const float*)d_in[3];
  const float* Wrec  = (const float*)d_in[4];
  const float* b_in  = (const float*)d_in[5];
  const float* b_rec = (const float*)d_in[6];
  float* out = (float*)d_out;

  // ---- persistent-MFMA path ws layout (ushort units) ----
  const size_t nWrecF = 6291456;    // 64*3*32*2*512
  const size_t nWinF  = 1572864;    // 64*3*8*2*512
  const size_t nhF    = 262144;     // 2 * 131072
  const size_t neF    = 33554432;   // 1024 * 32768
  const size_t needMF = (nWrecF + nWinF + nhF + neF) * sizeof(unsigned short);

  if (d_ws != nullptr && ws_size >= needMF + 4096) {
    unsigned short* WrecF = (unsigned short*)d_ws;
    unsigned short* WinF  = WrecF + nWrecF;
    unsigned short* hF    = WinF  + nWinF;
    unsigned short* eF    = hF    + nhF;
    unsigned*       flags = (unsigned*)((char*)d_ws + needMF);

    build_wfrag<<<64*3*32, 256, 0, stream>>>(Wrec, WrecF, 32);
    build_wfrag<<<64*3*8,  256, 0, stream>>>(Win,  WinF,  8);
    build_hfrag<<<256, 256, 0, stream>>>(init, hF);      // parity 0
    build_efrag<<<1024, 256, 0, stream>>>(x, emb, eF);
    init_flags<<<1, 256, 0, stream>>>(flags);

    gru_persistent<<<256, 256, 0, stream>>>(WrecF, WinF, hF, eF,
        init, b_in, b_rec, out, flags);
    return;
  }

  // ---- fallback: Round-0 f32 path ----
  float* WrecT = (float*)d_ws;
  float* WinT  = WrecT + (size_t)U3_ * U_;
  const size_t needT = ((size_t)U3_ * U_ + (size_t)U3_ * E_) * sizeof(float);
  const bool useWT = (d_ws != nullptr) && (ws_size >= needT);

  if (useWT) {
    transpose_f32<<<dim3(U3_/32, U_/32), 256, 0, stream>>>(Wrec, WrecT, U_, U3_);
    transpose_f32<<<dim3(U3_/32, E_/32), 256, 0, stream>>>(Win,  WinT,  E_, U3_);
    for (int t = 0; t < T_; ++t) {
      const float* hsrc = (t == 0) ? init : (out + (size_t)(t-1) * U_);
      const int hs = (t == 0) ? U_ : T_ * U_;
      gru_step<true><<<256, 512, 0, stream>>>(hsrc, hs, x, t, emb,
          Wrec, WrecT, Win, WinT, b_in, b_rec, out);
    }
  } else {
    for (int t = 0; t < T_; ++t) {
      const float* hsrc = (t == 0) ? init : (out + (size_t)(t-1) * U_);
      const int hs = (t == 0) ? U_ : T_ * U_;
      gru_step<false><<<256, 512, 0, stream>>>(hsrc, hs, x, t, emb,
          Wrec, WrecT, Win, WinT, b_in, b_rec, out);
    }
  }
}